// Round 10
// baseline (271.757 us; speedup 1.0000x reference)
//
#include <hip/hip_runtime.h>
#include <math.h>

#define UNITS 80
#define LATENT 128
#define IN_DIM 256
#define BATCH 8192
#define SEQ 256
#define G 320            // 4*UNITS
#define H2 160           // 2*UNITS
#define ROW_F4 (SEQ * UNITS / 4)   // 5120 f4 per batch row

#define TPB 640          // 10 waves; 640 % 20 == 0 (yc f4 period)
#define RPB 16           // contiguous rows per block (1.31 MB sweep)
#define NBLK (BATCH / RPB)   // 512 blocks (~2 per CU)

typedef float f4 __attribute__((ext_vector_type(4)));

__device__ __forceinline__ float sigf(float v) {
    return 1.0f / (1.0f + __expf(-v));
}

// ---------------------------------------------------------------------------
// Kernel 1: yc = decode_step(ones(128)). Input all-ones => z = colsum(K) + b.
// ---------------------------------------------------------------------------
__global__ __launch_bounds__(640)
void yc_kernel(const float* __restrict__ Kf, const float* __restrict__ bf,
               const float* __restrict__ Kb, const float* __restrict__ bb,
               const float* __restrict__ K1, const float* __restrict__ b1,
               float* __restrict__ yc) {
    __shared__ float z[2 * G];
    __shared__ float h[H2];
    const int t = threadIdx.x;   // 0..639

    {
        const float* K   = (t < G) ? Kf : Kb;
        const float* bia = (t < G) ? bf : bb;
        const int c = (t < G) ? t : t - G;
        float acc = bia[c];
#pragma unroll 8
        for (int l = 0; l < LATENT; ++l) acc += K[l * G + c];
        z[t] = acc;
    }
    __syncthreads();
    if (t < UNITS) {
        h[t] = sigf(z[240 + t]) * sigf(z[t]) * fmaxf(z[160 + t], 0.f);
    } else if (t >= G && t < G + UNITS) {
        const int u = t - G;
        h[UNITS + u] = sigf(z[G + 240 + u]) * sigf(z[G + u]) * fmaxf(z[G + 160 + u], 0.f);
    }
    __syncthreads();
    if (t < G) {
        float acc = b1[t];
#pragma unroll 8
        for (int l = 0; l < H2; ++l) acc = fmaf(h[l], K1[l * G + t], acc);
        z[t] = acc;
    }
    __syncthreads();
    if (t < UNITS) yc[t] = sigf(z[240 + t]) * sigf(z[t]) * fmaxf(z[160 + t], 0.f);
}

// ---------------------------------------------------------------------------
// Kernel 2: 512 blocks, 16 contiguous rows each.
//   Phase 1 (compute): block-cooperative y0 for all 16 rows into LDS
//                      (weights read ONCE per block).
//   Phase 2 (sweep):   ONE sequential nt-store cursor over the block's entire
//                      1.31 MB output region; s=0 slices folded into the
//                      first iteration of each row (640 % 20 == 0 keeps each
//                      thread's yc broadcast value constant).
// ---------------------------------------------------------------------------
__global__ __launch_bounds__(TPB)
void main_kernel(const float* __restrict__ x,
                 const float* __restrict__ Wl, const float* __restrict__ bl,
                 const float* __restrict__ Kf, const float* __restrict__ bf,
                 const float* __restrict__ Kb, const float* __restrict__ bb,
                 const float* __restrict__ K1, const float* __restrict__ b1,
                 const float* __restrict__ yc,
                 float* __restrict__ out) {
    __shared__ float xs[RPB * IN_DIM];     // 16 KB
    __shared__ float lat_s[RPB * LATENT];  // 8 KB
    __shared__ float h_s[RPB * H2];        // 10 KB
    __shared__ float y_s[RPB * UNITS];     // 5 KB

    const int t = threadIdx.x;
    const int R0 = blockIdx.x * RPB;

    // broadcast value for the s>=1 body: constant per thread
    const f4 yv = ((const f4*)yc)[t % (UNITS / 4)];

    // ---- stage x (16 rows x 256 f32 = 1024 f4) ----
    {
        const f4* xg = (const f4*)(x + (size_t)R0 * IN_DIM);
        for (int i = t; i < RPB * IN_DIM / 4; i += TPB) ((f4*)xs)[i] = xg[i];
    }
    __syncthreads();

    // ---- lat = x @ W_lat + b_lat : 16*128 = 2048 outputs ----
    for (int i = t; i < RPB * LATENT; i += TPB) {
        const int row = i >> 7, col = i & 127;
        float acc = bl[col];
        const float* xr = xs + row * IN_DIM;
#pragma unroll 8
        for (int l = 0; l < IN_DIM; ++l) acc = fmaf(xr[l], Wl[l * LATENT + col], acc);
        lat_s[i] = acc;
    }
    __syncthreads();

    // ---- fw/bw gates: 2*16*80 = 2560 outputs (f dead: c0=0; relu(c)=c) ----
    for (int i = t; i < 2 * RPB * UNITS; i += TPB) {
        const int half = (i >= RPB * UNITS);
        const int j = half ? i - RPB * UNITS : i;
        const int row = j / UNITS;
        const int u = j - row * UNITS;
        const float* K   = half ? Kb : Kf;
        const float* bia = half ? bb : bf;
        float ai = bia[u], ac = bia[160 + u], ao = bia[240 + u];
        const float* lr = lat_s + row * LATENT;
#pragma unroll 4
        for (int k = 0; k < LATENT; ++k) {
            const float lv = lr[k];
            ai = fmaf(lv, K[k * G + u], ai);
            ac = fmaf(lv, K[k * G + 160 + u], ac);
            ao = fmaf(lv, K[k * G + 240 + u], ao);
        }
        h_s[row * H2 + half * UNITS + u] = sigf(ao) * sigf(ai) * fmaxf(ac, 0.f);
    }
    __syncthreads();

    // ---- output LSTM: 16*80 = 2560... 1280 outputs -> y_s ----
    for (int i = t; i < RPB * UNITS; i += TPB) {
        const int row = i / UNITS;
        const int u = i - row * UNITS;
        float ai = b1[u], ac = b1[160 + u], ao = b1[240 + u];
        const float* hr = h_s + row * H2;
#pragma unroll 4
        for (int k = 0; k < H2; ++k) {
            const float hv = hr[k];
            ai = fmaf(hv, K1[k * G + u], ai);
            ac = fmaf(hv, K1[k * G + 160 + u], ac);
            ao = fmaf(hv, K1[k * G + 240 + u], ao);
        }
        y_s[i] = sigf(ao) * sigf(ai) * fmaxf(ac, 0.f);
    }
    __syncthreads();

    // keep the sweep strictly after all load-uses (no vmcnt interlock)
    __builtin_amdgcn_sched_barrier(0);

    // ---- phase 2: one sequential nt sweep over [R0, R0+16) rows ----
    {
        f4* out4 = (f4*)out;
        const f4* ys4 = (const f4*)y_s;    // [16][20] f4, rows 16B-aligned
        for (int r = 0; r < RPB; ++r) {
            f4* rowp = out4 + (size_t)(R0 + r) * ROW_F4;
            // k = 0: threads 0..19 write the s=0 slice, the rest write body
            const f4 v0 = (t < UNITS / 4) ? ys4[r * (UNITS / 4) + t] : yv;
            __builtin_nontemporal_store(v0, rowp + t);
#pragma unroll
            for (int k = 1; k < ROW_F4 / TPB; ++k)      // k = 1..7
                __builtin_nontemporal_store(yv, rowp + t + k * TPB);
        }
    }
}

extern "C" void kernel_launch(void* const* d_in, const int* in_sizes, int n_in,
                              void* d_out, int out_size, void* d_ws, size_t ws_size,
                              hipStream_t stream) {
    const float* x   = (const float*)d_in[0];
    // d_in[1] = size (scalar, fixed 256)
    const float* Wl  = (const float*)d_in[2];
    const float* bl  = (const float*)d_in[3];
    const float* Kf  = (const float*)d_in[4];
    const float* bf  = (const float*)d_in[5];
    const float* Kb  = (const float*)d_in[6];
    const float* bb  = (const float*)d_in[7];
    const float* K1  = (const float*)d_in[8];
    const float* b1  = (const float*)d_in[9];
    float* out = (float*)d_out;
    float* yc  = (float*)d_ws;   // 80 floats

    yc_kernel<<<1, 640, 0, stream>>>(Kf, bf, Kb, bb, K1, b1, yc);
    main_kernel<<<NBLK, TPB, 0, stream>>>(x, Wl, bl, Kf, bf, Kb, bb, K1, b1, yc, out);
}